// Round 3
// baseline (1919.146 us; speedup 1.0000x reference)
//
#include <hip/hip_runtime.h>
#include <math.h>

#define NN 50000
#define EE 800000
#define KHALF 25000
#define RCH 4096

// ---------------- CSR build ----------------
__global__ void k_hist(const int* __restrict__ dst, int* __restrict__ cnt, int E){
  int i = blockIdx.x*blockDim.x + threadIdx.x;
  if(i<E) atomicAdd(&cnt[dst[i]], 1);
}

__global__ void k_scan(const int* __restrict__ deg, int* __restrict__ rowptr, int n){
  __shared__ int sm[1024];
  int t = threadIdx.x;
  int chunk = (n + 1023) >> 10;
  int b = t*chunk; int e = b+chunk; if(b>n) b=n; if(e>n) e=n;
  int s=0;
  for(int i=b;i<e;i++) s += deg[i];
  sm[t]=s; __syncthreads();
  for(int off=1; off<1024; off<<=1){
    int add = (t>=off)? sm[t-off] : 0;
    __syncthreads();
    sm[t] += add;
    __syncthreads();
  }
  int run = sm[t]-s;
  for(int i=b;i<e;i++){ rowptr[i]=run; run += deg[i]; }
  if(t==1023) rowptr[n]=sm[1023];
}

__global__ void k_fill(const int* __restrict__ src, const int* __restrict__ dst,
                       const int* __restrict__ rowptr, int* __restrict__ cnt,
                       int* __restrict__ csr, int E){
  int i = blockIdx.x*blockDim.x + threadIdx.x;
  if(i<E){
    int d = dst[i];
    int p = rowptr[d] + atomicAdd(&cnt[d],1);
    csr[p] = src[i];
  }
}

// ---------------- segment mean (wave per node, vectorized gather) ----------------
// lane covers cols [lane*VW, lane*VW+VW); serial CSR-order accumulate => deterministic.
// conv1 instance (AccT=double, VW=1) is bit-identical to the verified f64 path.
template<typename AccT, typename OT, int F, int VW>
__global__ void k_segmean(const float* __restrict__ x, const int* __restrict__ csr,
                          const int* __restrict__ rowptr, OT* __restrict__ out, int n){
  int gid = blockIdx.x*blockDim.x + threadIdx.x;
  int node = gid >> 6; int lane = gid & 63;
  if(node>=n) return;
  int b = rowptr[node], e = rowptr[node+1];
  AccT acc[VW];
  #pragma unroll
  for(int k=0;k<VW;k++) acc[k]=(AccT)0;
  const float* xp = x + lane*VW;
  for(int j=b;j<e;j++){
    const float* row = xp + (long)csr[j]*F;
    if(VW==1){
      acc[0] += (AccT)row[0];
    } else if(VW==2){
      float2 v = *(const float2*)row;
      acc[0]+=(AccT)v.x; acc[1]+=(AccT)v.y;
    } else {
      float4 v = *(const float4*)row;
      acc[0]+=(AccT)v.x; acc[1]+=(AccT)v.y; acc[2]+=(AccT)v.z; acc[3]+=(AccT)v.w;
    }
  }
  int d = e-b; if(d<1) d=1;
  AccT inv = (AccT)1 / (AccT)d;
  #pragma unroll
  for(int k=0;k<VW;k++) out[(long)node*F + lane*VW + k] = (OT)(acc[k]*inv);
}

// ---------------- generic dual-operand f32 GEMM ----------------
__global__ __launch_bounds__(256) void k_gemm_f32(
    const float* __restrict__ A, const float* __restrict__ W1, int K1,
    const float* __restrict__ X, const float* __restrict__ W2, int K2,
    const float* __restrict__ bias,
    float* __restrict__ out, float* __restrict__ outB,
    int M, int J, int relu, int split)
{
  __shared__ float As[32][68];
  __shared__ float Ws[32][64];
  const int m0 = blockIdx.x*64, n0 = blockIdx.y*64;
  const int t = threadIdx.x;
  const int tm = t & 15, tn = t >> 4;
  float acc[4][4];
  #pragma unroll
  for(int i=0;i<4;i++)
    #pragma unroll
    for(int j=0;j<4;j++) acc[i][j]=0.f;

  for(int pair=0; pair<2; pair++){
    const float* Ain = pair ? X : A;
    const float* Win = pair ? W2 : W1;
    int K = pair ? K2 : K1;
    if(K<=0) continue;
    for(int k0=0; k0<K; k0+=32){
      #pragma unroll
      for(int i=0;i<8;i++){
        int idx = t + i*256;
        int r = idx >> 5, c = idx & 31;
        int gr = m0 + r;
        As[c][r] = (gr<M) ? Ain[(long)gr*K + k0 + c] : 0.f;
      }
      #pragma unroll
      for(int i=0;i<8;i++){
        int idx = t + i*256;
        int r = idx >> 6, c = idx & 63;
        Ws[r][c] = Win[(long)(k0+r)*J + n0 + c];
      }
      __syncthreads();
      #pragma unroll
      for(int kk=0;kk<32;kk++){
        float4 a = *(const float4*)&As[kk][tm*4];
        float4 w = *(const float4*)&Ws[kk][tn*4];
        acc[0][0] += a.x*w.x; acc[0][1] += a.x*w.y; acc[0][2] += a.x*w.z; acc[0][3] += a.x*w.w;
        acc[1][0] += a.y*w.x; acc[1][1] += a.y*w.y; acc[1][2] += a.y*w.z; acc[1][3] += a.y*w.w;
        acc[2][0] += a.z*w.x; acc[2][1] += a.z*w.y; acc[2][2] += a.z*w.z; acc[2][3] += a.z*w.w;
        acc[3][0] += a.w*w.x; acc[3][1] += a.w*w.y; acc[3][2] += a.w*w.z; acc[3][3] += a.w*w.w;
      }
      __syncthreads();
    }
  }
  #pragma unroll
  for(int i=0;i<4;i++){
    int gr = m0 + tm*4 + i;
    if(gr>=M) continue;
    #pragma unroll
    for(int j=0;j<4;j++){
      int gc = n0 + tn*4 + j;
      float v = acc[i][j] + bias[gc];
      if(relu) v = fmaxf(v,0.f);
      if(!split) out[(long)gr*J + gc] = v;
      else {
        if(gc<64) out[(long)gr*64 + gc] = v;
        else      outB[(long)gr*64 + (gc-64)] = v;
      }
    }
  }
}

// ---------------- conv1 GEMM in f64 (score-critical path) ----------------
__global__ __launch_bounds__(256) void k_gemm_c1(
    const double* __restrict__ A1, const float* __restrict__ X,
    const float* __restrict__ W1, const float* __restrict__ W2,
    const float* __restrict__ bias, double* __restrict__ out, int M)
{
  __shared__ double As[32][66];
  __shared__ double Ws[32][64];
  const int m0 = blockIdx.x*64, n0 = blockIdx.y*64;
  const int t = threadIdx.x;
  const int tm = t & 15, tn = t >> 4;
  double acc[4][4];
  #pragma unroll
  for(int i=0;i<4;i++)
    #pragma unroll
    for(int j=0;j<4;j++) acc[i][j]=0.0;

  for(int pair=0; pair<2; pair++){
    const float* Wp = pair ? W2 : W1;
    for(int k0=0; k0<64; k0+=32){
      #pragma unroll
      for(int i=0;i<8;i++){
        int idx = t + i*256;
        int r = idx >> 5, c = idx & 31;
        int gr = m0 + r;
        double v = 0.0;
        if(gr<M) v = pair ? (double)X[(long)gr*64 + k0 + c] : A1[(long)gr*64 + k0 + c];
        As[c][r] = v;
      }
      #pragma unroll
      for(int i=0;i<8;i++){
        int idx = t + i*256;
        int r = idx >> 6, c = idx & 63;
        Ws[r][c] = (double)Wp[(k0+r)*128 + n0 + c];
      }
      __syncthreads();
      #pragma unroll
      for(int kk=0;kk<32;kk++){
        double a0=As[kk][tm*4+0], a1=As[kk][tm*4+1], a2=As[kk][tm*4+2], a3=As[kk][tm*4+3];
        double w0=Ws[kk][tn*4+0], w1=Ws[kk][tn*4+1], w2=Ws[kk][tn*4+2], w3=Ws[kk][tn*4+3];
        acc[0][0] += a0*w0; acc[0][1] += a0*w1; acc[0][2] += a0*w2; acc[0][3] += a0*w3;
        acc[1][0] += a1*w0; acc[1][1] += a1*w1; acc[1][2] += a1*w2; acc[1][3] += a1*w3;
        acc[2][0] += a2*w0; acc[2][1] += a2*w1; acc[2][2] += a2*w2; acc[2][3] += a2*w3;
        acc[3][0] += a3*w0; acc[3][1] += a3*w1; acc[3][2] += a3*w2; acc[3][3] += a3*w3;
      }
      __syncthreads();
    }
  }
  #pragma unroll
  for(int i=0;i<4;i++){
    int gr = m0 + tm*4 + i;
    if(gr>=M) continue;
    #pragma unroll
    for(int j=0;j<4;j++){
      int gc = n0 + tn*4 + j;
      double v = acc[i][j] + (double)bias[gc];
      if(v<0.0) v=0.0;
      out[(long)gr*128 + gc] = v;
    }
  }
}

// ---------------- batchnorm ----------------
template<typename T>
__global__ void k_colstats(const T* __restrict__ x, int M, int J,
                           double* __restrict__ ps, double* __restrict__ pq){
  int c = threadIdx.x; int b = blockIdx.x, B = gridDim.x;
  int rows = (M + B - 1)/B;
  int r0 = b*rows, r1 = r0+rows; if(r1>M) r1=M;
  double s=0.0,q=0.0;
  for(int r=r0;r<r1;r++){ double v = (double)x[(long)r*J + c]; s+=v; q+=v*v; }
  ps[(long)b*J+c]=s; pq[(long)b*J+c]=q;
}

__global__ void k_bnfinal(const double* __restrict__ ps, const double* __restrict__ pq,
                          int B, int J, int M, const float* __restrict__ g,
                          const float* __restrict__ bta,
                          double* __restrict__ sc, double* __restrict__ sh){
  int c = threadIdx.x; if(c>=J) return;
  double s=0.0,q=0.0;
  for(int b=0;b<B;b++){ s+=ps[(long)b*J+c]; q+=pq[(long)b*J+c]; }
  double m = s/M; double v = q/M - m*m;
  double inv = 1.0/sqrt(v + 1e-5);
  double a = (double)g[c]*inv;
  sc[c]=a; sh[c]=(double)bta[c] - m*a;
}

__global__ void k_bnapply_f64(double* __restrict__ x, float* __restrict__ o32,
                              const double* __restrict__ sc, const double* __restrict__ sh,
                              long total, int Jm){
  long i = (long)blockIdx.x*blockDim.x + threadIdx.x;
  if(i>=total) return;
  int c = (int)(i & Jm);
  double v = x[i]*sc[c] + sh[c];
  x[i]=v; o32[i]=(float)v;
}

__global__ void k_bnapply_f32(float* __restrict__ x,
                              const double* __restrict__ sc, const double* __restrict__ sh,
                              long total, int Jm){
  long i = (long)blockIdx.x*blockDim.x + threadIdx.x;
  if(i>=total) return;
  int c = (int)(i & Jm);
  x[i] = (float)((double)x[i]*sc[c] + sh[c]);
}

// ---------------- z = mean + exp(log_std) * noise.mean(0), float4 ----------------
__global__ void k_z(const float* __restrict__ mean, const float* __restrict__ lstd,
                    const float* __restrict__ noise, float* __restrict__ z, int total4){
  int i = blockIdx.x*blockDim.x + threadIdx.x;
  if(i>=total4) return;
  const float4* m4 = (const float4*)mean;
  const float4* l4 = (const float4*)lstd;
  const float4* n4 = (const float4*)noise;
  float4 m = m4[i], l = l4[i];
  float nx=0.f, ny=0.f, nz=0.f, nw=0.f;
  #pragma unroll
  for(int s=0;s<10;s++){
    float4 v = n4[(long)s*total4 + i];
    nx+=v.x; ny+=v.y; nz+=v.z; nw+=v.w;
  }
  float4 o;
  o.x = (float)((double)m.x + exp((double)l.x)*((double)nx*0.1));
  o.y = (float)((double)m.y + exp((double)l.y)*((double)ny*0.1));
  o.z = (float)((double)m.z + exp((double)l.z)*((double)nz*0.1));
  o.w = (float)((double)m.w + exp((double)l.w)*((double)nw*0.1));
  ((float4*)z)[i] = o;
}

// ---------------- pooling score path (f64) ----------------
__global__ void k_tr(const double* __restrict__ x1, const float* __restrict__ wrel,
                     const float* __restrict__ wroot, double* __restrict__ t,
                     double* __restrict__ r, int n){
  int gid = blockIdx.x*blockDim.x + threadIdx.x;
  int node = gid>>6, lane = gid&63;
  if(node>=n) return;
  const double* row = x1 + (long)node*128;
  double a0=row[lane], a1=row[lane+64];
  double tv = a0*(double)wrel[lane]  + a1*(double)wrel[lane+64];
  double rv = a0*(double)wroot[lane] + a1*(double)wroot[lane+64];
  for(int off=32; off>0; off>>=1){
    tv += __shfl_xor(tv, off);
    rv += __shfl_xor(rv, off);
  }
  if(lane==0){ t[node]=tv; r[node]=rv; }
}

// score -> monotone u64 key (-0 normalized; tanh never NaN)
__global__ void k_score(const double* __restrict__ t, const double* __restrict__ r,
                        const int* __restrict__ csr, const int* __restrict__ rowptr,
                        const float* __restrict__ bp,
                        unsigned long long* __restrict__ key, int n){
  int i = blockIdx.x*blockDim.x + threadIdx.x;
  if(i>=n) return;
  double s = (double)bp[0] + r[i];
  int b=rowptr[i], e=rowptr[i+1];
  for(int j=b;j<e;j++) s += t[csr[j]];
  double sc = tanh(s) + 0.0;           // -0 -> +0
  long long u = __double_as_longlong(sc);
  unsigned long long uu = (unsigned long long)u;
  key[i] = (u < 0) ? ~uu : (uu ^ 0x8000000000000000ULL);
}

// rank_i = #{all j : k_j > k_i} + #{j < i : k_j == k_i}
// single fused pass, ulonglong2 LDS reads, partials combined by int atomicAdd
__global__ __launch_bounds__(256) void k_rank_part(const unsigned long long* __restrict__ key,
                                                   int n, int* __restrict__ cnt){
  __shared__ unsigned long long sm[RCH + 2];
  int i = blockIdx.x*256 + threadIdx.x;
  int base = blockIdx.y*RCH;
  int lim = n - base; if(lim > RCH) lim = RCH;
  for(int u=threadIdx.x; u<lim; u+=256) sm[u] = key[base+u];
  if(threadIdx.x==0 && (lim&1)) sm[lim] = 0ULL;   // pad: 0 < any valid key, never equal
  __syncthreads();
  if(i>=n) return;
  unsigned long long ai = key[i];
  int us = i - base; if(us<0) us=0; if(us>lim) us=lim;
  int lim2 = (lim+1)&~1;
  int c=0;
  #pragma unroll 4
  for(int u=0; u<lim2; u+=2){
    ulonglong2 v = *(const ulonglong2*)&sm[u];
    c += (v.x > ai) ? 1 : 0;
    c += (v.y > ai) ? 1 : 0;
    c += ((v.x == ai) && (u   < us)) ? 1 : 0;
    c += ((v.y == ai) && (u+1 < us)) ? 1 : 0;
  }
  if(c) atomicAdd(&cnt[i], c);
}

__global__ void k_rank_fin(const int* __restrict__ cnt, int n, int k,
                           int* __restrict__ keep, int* __restrict__ perm){
  int i = blockIdx.x*blockDim.x + threadIdx.x;
  if(i>=n) return;
  int c = cnt[i];
  int kp = (c<k) ? 1 : 0;
  keep[i]=kp;
  if(kp) perm[c]=i;
}

__global__ void k_unpool(const float* __restrict__ x1, const int* __restrict__ perm,
                         float* __restrict__ out, int k){
  int i = blockIdx.x*blockDim.x + threadIdx.x;
  if(i >= k*128) return;
  int r = i>>7, c = i&127;
  out[i] = x1[(long)perm[r]*128 + c];
}

__global__ void k_edgeout(const int* __restrict__ src, const int* __restrict__ dst,
                          const int* __restrict__ keep, float* __restrict__ o2,
                          float* __restrict__ o3, int E){
  int e = blockIdx.x*blockDim.x + threadIdx.x;
  if(e>=E) return;
  int s=src[e], d=dst[e];
  bool m = keep[s] && keep[d];
  o2[e]   = m ? (float)s : -1.f;
  o2[E+e] = m ? (float)d : -1.f;
  o3[e]   = m ? 1.f : 0.f;
}

// ---------------- launch ----------------
extern "C" void kernel_launch(void* const* d_in, const int* in_sizes, int n_in,
                              void* d_out, int out_size, void* d_ws, size_t ws_size,
                              hipStream_t stream){
  const float* x     = (const float*)d_in[0];
  const int*   ei    = (const int*)d_in[1];
  const float* noise = (const float*)d_in[3];
  const float* We1l  = (const float*)d_in[4];
  const float* be1   = (const float*)d_in[5];
  const float* We1r  = (const float*)d_in[6];
  const float* g1    = (const float*)d_in[7];
  const float* b1    = (const float*)d_in[8];
  const float* We2l  = (const float*)d_in[9];
  const float* be2   = (const float*)d_in[10];
  const float* We2r  = (const float*)d_in[11];
  const float* g2    = (const float*)d_in[12];
  const float* b2    = (const float*)d_in[13];
  const float* We3l  = (const float*)d_in[14];
  const float* be3   = (const float*)d_in[15];
  const float* We3r  = (const float*)d_in[16];
  const float* Wt    = (const float*)d_in[17];
  const float* bt    = (const float*)d_in[18];
  const float* Wd1   = (const float*)d_in[19];
  const float* bd1   = (const float*)d_in[20];
  const float* gd    = (const float*)d_in[21];
  const float* bd    = (const float*)d_in[22];
  const float* Wd2   = (const float*)d_in[23];
  const float* bd2   = (const float*)d_in[24];
  const float* Wprel = (const float*)d_in[25];
  const float* bp    = (const float*)d_in[26];
  const float* Wproot= (const float*)d_in[27];

  const int* src = ei;
  const int* dst = ei + EE;

  float* out   = (float*)d_out;
  float* o_rec  = out;                 // N*64
  float* o_xun  = out + 3200000;       // k*128
  float* o_eiu  = out + 6400000;       // 2*E
  float* o_mask = out + 8000000;       // E
  float* o_mean = out + 8800000;       // N*64
  float* o_lstd = out + 12000000;      // N*64
  float* o_x1   = out + 15200000;      // N*128

  char* w = (char*)d_ws;
  size_t off = 0;
  auto alloc = [&](size_t bytes)->char*{
    char* p = w + off; off += (bytes + 255) & ~(size_t)255; return p;
  };
  int*    csr  = (int*)   alloc((size_t)EE*4);
  int*    rowp = (int*)   alloc((size_t)(NN+1)*4);
  int*    cnt  = (int*)   alloc((size_t)NN*4);
  char*   B3   =          alloc((size_t)NN*128*8);
  char*   B4   =          alloc((size_t)NN*64*8);
  char*   B5   =          alloc((size_t)NN*256*4);
  double* t_   = (double*)alloc((size_t)NN*8);
  double* r_   = (double*)alloc((size_t)NN*8);
  unsigned long long* key_ = (unsigned long long*)alloc((size_t)NN*8);
  int*    keep = (int*)   alloc((size_t)NN*4);
  int*    perm = (int*)   alloc((size_t)KHALF*4);
  double* ps   = (double*)alloc((size_t)240*256*8);
  double* pq   = (double*)alloc((size_t)240*256*8);
  double* bnsc = (double*)alloc(256*8);
  double* bnsh = (double*)alloc(256*8);
  (void)in_sizes; (void)n_in; (void)out_size; (void)ws_size;

  double* A1  = (double*)B4;
  double* x1p = (double*)B3;
  float*  A2  = (float*)B4;
  float*  x2  = (float*)B3;
  float*  A3  = (float*)B5;
  float*  zb  = (float*)B5;
  float*  x1t = (float*)(B5 + (size_t)NN*64*4);
  float*  h   = (float*)B4;

  // CSR build
  hipMemsetAsync(cnt, 0, (size_t)NN*4, stream);
  k_hist<<<(EE+255)/256,256,0,stream>>>(dst, cnt, EE);
  k_scan<<<1,1024,0,stream>>>(cnt, rowp, NN);
  hipMemsetAsync(cnt, 0, (size_t)NN*4, stream);
  k_fill<<<(EE+255)/256,256,0,stream>>>(src, dst, rowp, cnt, csr, EE);

  // conv1 (f64 score-critical path; segmean instance bit-identical to R2)
  k_segmean<double,double,64,1><<<(NN+3)/4,256,0,stream>>>(x, csr, rowp, A1, NN);
  { dim3 g((NN+63)/64, 2);
    k_gemm_c1<<<g,256,0,stream>>>(A1, x, We1l, We1r, be1, x1p, NN); }
  k_colstats<double><<<240,128,0,stream>>>(x1p, NN, 128, ps, pq);
  k_bnfinal<<<1,128,0,stream>>>(ps,pq,240,128,NN,g1,b1,bnsc,bnsh);
  { long tot=(long)NN*128;
    k_bnapply_f64<<<(int)((tot+255)/256),256,0,stream>>>(x1p, o_x1, bnsc,bnsh, tot, 127); }
  k_tr<<<(NN+3)/4,256,0,stream>>>(x1p, Wprel, Wproot, t_, r_, NN);

  // conv2 (f32)
  k_segmean<float,float,128,2><<<(NN+3)/4,256,0,stream>>>(o_x1, csr, rowp, A2, NN);
  { dim3 g((NN+63)/64, 4);
    k_gemm_f32<<<g,256,0,stream>>>(A2, We2l, 128, o_x1, We2r, 128, be2, x2, nullptr, NN, 256, 1, 0); }
  k_colstats<float><<<240,256,0,stream>>>(x2, NN, 256, ps, pq);
  k_bnfinal<<<1,256,0,stream>>>(ps,pq,240,256,NN,g2,b2,bnsc,bnsh);
  { long tot=(long)NN*256;
    k_bnapply_f32<<<(int)((tot+255)/256),256,0,stream>>>(x2, bnsc,bnsh, tot, 255); }

  // conv3 -> mean / log_std
  k_segmean<float,float,256,4><<<(NN+3)/4,256,0,stream>>>(x2, csr, rowp, A3, NN);
  { dim3 g((NN+63)/64, 2);
    k_gemm_f32<<<g,256,0,stream>>>(A3, We3l, 256, x2, We3r, 256, be3, o_mean, o_lstd, NN, 128, 0, 1); }

  // decoder
  k_z<<<(800000+255)/256,256,0,stream>>>(o_mean, o_lstd, noise, zb, 800000);
  { dim3 g((NN+63)/64, 1);
    k_gemm_f32<<<g,256,0,stream>>>(o_x1, Wt, 128, nullptr, nullptr, 0, bt, x1t, nullptr, NN, 64, 0, 0); }
  { dim3 g((NN+63)/64, 2);
    k_gemm_f32<<<g,256,0,stream>>>(zb, Wd1, 64, x1t, Wd1 + 64*128, 64, bd1, h, nullptr, NN, 128, 1, 0); }
  k_colstats<float><<<240,128,0,stream>>>(h, NN, 128, ps, pq);
  k_bnfinal<<<1,128,0,stream>>>(ps,pq,240,128,NN,gd,bd,bnsc,bnsh);
  { long tot=(long)NN*128;
    k_bnapply_f32<<<(int)((tot+255)/256),256,0,stream>>>(h, bnsc,bnsh, tot, 127); }
  { dim3 g((NN+63)/64, 1);
    k_gemm_f32<<<g,256,0,stream>>>(h, Wd2, 128, nullptr, nullptr, 0, bd2, o_rec, nullptr, NN, 64, 0, 0); }

  // pooling: score/key -> parallel exact rank -> outputs
  k_score<<<(NN+255)/256,256,0,stream>>>(t_, r_, csr, rowp, bp, key_, NN);
  hipMemsetAsync(cnt, 0, (size_t)NN*4, stream);
  { dim3 g((NN+255)/256, (NN+RCH-1)/RCH);
    k_rank_part<<<g,256,0,stream>>>(key_, NN, cnt); }
  k_rank_fin<<<(NN+255)/256,256,0,stream>>>(cnt, NN, KHALF, keep, perm);
  k_unpool<<<(KHALF*128+255)/256,256,0,stream>>>(o_x1, perm, o_xun, KHALF);
  k_edgeout<<<(EE+255)/256,256,0,stream>>>(src, dst, keep, o_eiu, o_mask, EE);
}

// Round 4
// 1563.242 us; speedup vs baseline: 1.2277x; 1.2277x over previous
//
#include <hip/hip_runtime.h>
#include <math.h>

#define NN 50000
#define EE 800000
#define KHALF 25000
#define NSAMP 2048
#define NBK (NSAMP+1)

// ---------------- CSR build ----------------
__global__ void k_hist(const int* __restrict__ dst, int* __restrict__ cnt, int E){
  int i = blockIdx.x*blockDim.x + threadIdx.x;
  if(i<E) atomicAdd(&cnt[dst[i]], 1);
}

__global__ void k_scan(const int* __restrict__ deg, int* __restrict__ rowptr, int n){
  __shared__ int sm[1024];
  int t = threadIdx.x;
  int chunk = (n + 1023) >> 10;
  int b = t*chunk; int e = b+chunk; if(b>n) b=n; if(e>n) e=n;
  int s=0;
  for(int i=b;i<e;i++) s += deg[i];
  sm[t]=s; __syncthreads();
  for(int off=1; off<1024; off<<=1){
    int add = (t>=off)? sm[t-off] : 0;
    __syncthreads();
    sm[t] += add;
    __syncthreads();
  }
  int run = sm[t]-s;
  for(int i=b;i<e;i++){ rowptr[i]=run; run += deg[i]; }
  if(t==1023) rowptr[n]=sm[1023];
}

__global__ void k_fill(const int* __restrict__ src, const int* __restrict__ dst,
                       const int* __restrict__ rowptr, int* __restrict__ cnt,
                       int* __restrict__ csr, int E){
  int i = blockIdx.x*blockDim.x + threadIdx.x;
  if(i<E){
    int d = dst[i];
    int p = rowptr[d] + atomicAdd(&cnt[d],1);
    csr[p] = src[i];
  }
}

// ---------------- segment mean (wave per node, vectorized gather) ----------------
template<typename AccT, typename OT, int F, int VW>
__global__ void k_segmean(const float* __restrict__ x, const int* __restrict__ csr,
                          const int* __restrict__ rowptr, OT* __restrict__ out, int n){
  int gid = blockIdx.x*blockDim.x + threadIdx.x;
  int node = gid >> 6; int lane = gid & 63;
  if(node>=n) return;
  int b = rowptr[node], e = rowptr[node+1];
  AccT acc[VW];
  #pragma unroll
  for(int k=0;k<VW;k++) acc[k]=(AccT)0;
  const float* xp = x + lane*VW;
  for(int j=b;j<e;j++){
    const float* row = xp + (long)csr[j]*F;
    if(VW==1){
      acc[0] += (AccT)row[0];
    } else if(VW==2){
      float2 v = *(const float2*)row;
      acc[0]+=(AccT)v.x; acc[1]+=(AccT)v.y;
    } else {
      float4 v = *(const float4*)row;
      acc[0]+=(AccT)v.x; acc[1]+=(AccT)v.y; acc[2]+=(AccT)v.z; acc[3]+=(AccT)v.w;
    }
  }
  int d = e-b; if(d<1) d=1;
  AccT inv = (AccT)1 / (AccT)d;
  #pragma unroll
  for(int k=0;k<VW;k++) out[(long)node*F + lane*VW + k] = (OT)(acc[k]*inv);
}

// segmean(T3) + msr, split-written to mean/lstd (conv3 transform-first epilogue)
__global__ void k_segmean_ms(const float* __restrict__ T3, const float* __restrict__ msr,
                             const int* __restrict__ csr, const int* __restrict__ rowptr,
                             float* __restrict__ omean, float* __restrict__ olstd, int n){
  int gid = blockIdx.x*blockDim.x + threadIdx.x;
  int node = gid >> 6; int lane = gid & 63;
  if(node>=n) return;
  int b = rowptr[node], e = rowptr[node+1];
  float a0=0.f, a1=0.f;
  const float* xp = T3 + lane*2;
  for(int j=b;j<e;j++){
    float2 v = *(const float2*)(xp + (long)csr[j]*128);
    a0+=v.x; a1+=v.y;
  }
  int d=e-b; if(d<1)d=1;
  float inv = 1.f/(float)d;
  float2 mv = *(const float2*)(msr + (long)node*128 + lane*2);
  float2 r; r.x = a0*inv + mv.x; r.y = a1*inv + mv.y;
  int c0 = lane*2;   // pair never straddles the 64-col split
  if(c0 < 64) *(float2*)(omean + (long)node*64 + c0)      = r;
  else        *(float2*)(olstd + (long)node*64 + (c0-64)) = r;
}

// ---------------- generic dual-operand f32 GEMM ----------------
__global__ __launch_bounds__(256) void k_gemm_f32(
    const float* __restrict__ A, const float* __restrict__ W1, int K1,
    const float* __restrict__ X, const float* __restrict__ W2, int K2,
    const float* __restrict__ bias,
    float* __restrict__ out, float* __restrict__ outB,
    int M, int J, int relu, int split)
{
  __shared__ float As[32][68];
  __shared__ float Ws[32][64];
  const int m0 = blockIdx.x*64, n0 = blockIdx.y*64;
  const int t = threadIdx.x;
  const int tm = t & 15, tn = t >> 4;
  float acc[4][4];
  #pragma unroll
  for(int i=0;i<4;i++)
    #pragma unroll
    for(int j=0;j<4;j++) acc[i][j]=0.f;

  for(int pair=0; pair<2; pair++){
    const float* Ain = pair ? X : A;
    const float* Win = pair ? W2 : W1;
    int K = pair ? K2 : K1;
    if(K<=0) continue;
    for(int k0=0; k0<K; k0+=32){
      #pragma unroll
      for(int i=0;i<8;i++){
        int idx = t + i*256;
        int r = idx >> 5, c = idx & 31;
        int gr = m0 + r;
        As[c][r] = (gr<M) ? Ain[(long)gr*K + k0 + c] : 0.f;
      }
      #pragma unroll
      for(int i=0;i<8;i++){
        int idx = t + i*256;
        int r = idx >> 6, c = idx & 63;
        Ws[r][c] = Win[(long)(k0+r)*J + n0 + c];
      }
      __syncthreads();
      #pragma unroll
      for(int kk=0;kk<32;kk++){
        float4 a = *(const float4*)&As[kk][tm*4];
        float4 w = *(const float4*)&Ws[kk][tn*4];
        acc[0][0] += a.x*w.x; acc[0][1] += a.x*w.y; acc[0][2] += a.x*w.z; acc[0][3] += a.x*w.w;
        acc[1][0] += a.y*w.x; acc[1][1] += a.y*w.y; acc[1][2] += a.y*w.z; acc[1][3] += a.y*w.w;
        acc[2][0] += a.z*w.x; acc[2][1] += a.z*w.y; acc[2][2] += a.z*w.z; acc[2][3] += a.z*w.w;
        acc[3][0] += a.w*w.x; acc[3][1] += a.w*w.y; acc[3][2] += a.w*w.z; acc[3][3] += a.w*w.w;
      }
      __syncthreads();
    }
  }
  #pragma unroll
  for(int i=0;i<4;i++){
    int gr = m0 + tm*4 + i;
    if(gr>=M) continue;
    #pragma unroll
    for(int j=0;j<4;j++){
      int gc = n0 + tn*4 + j;
      float v = acc[i][j] + (bias ? bias[gc] : 0.f);
      if(relu) v = fmaxf(v,0.f);
      if(!split) out[(long)gr*J + gc] = v;
      else {
        if(gc<64) out[(long)gr*64 + gc] = v;
        else      outB[(long)gr*64 + (gc-64)] = v;
      }
    }
  }
}

// ---------------- conv1 GEMM in f64 (score-critical path) ----------------
__global__ __launch_bounds__(256) void k_gemm_c1(
    const double* __restrict__ A1, const float* __restrict__ X,
    const float* __restrict__ W1, const float* __restrict__ W2,
    const float* __restrict__ bias, double* __restrict__ out, int M)
{
  __shared__ double As[32][66];
  __shared__ double Ws[32][64];
  const int m0 = blockIdx.x*64, n0 = blockIdx.y*64;
  const int t = threadIdx.x;
  const int tm = t & 15, tn = t >> 4;
  double acc[4][4];
  #pragma unroll
  for(int i=0;i<4;i++)
    #pragma unroll
    for(int j=0;j<4;j++) acc[i][j]=0.0;

  for(int pair=0; pair<2; pair++){
    const float* Wp = pair ? W2 : W1;
    for(int k0=0; k0<64; k0+=32){
      #pragma unroll
      for(int i=0;i<8;i++){
        int idx = t + i*256;
        int r = idx >> 5, c = idx & 31;
        int gr = m0 + r;
        double v = 0.0;
        if(gr<M) v = pair ? (double)X[(long)gr*64 + k0 + c] : A1[(long)gr*64 + k0 + c];
        As[c][r] = v;
      }
      #pragma unroll
      for(int i=0;i<8;i++){
        int idx = t + i*256;
        int r = idx >> 6, c = idx & 63;
        Ws[r][c] = (double)Wp[(k0+r)*128 + n0 + c];
      }
      __syncthreads();
      #pragma unroll
      for(int kk=0;kk<32;kk++){
        double a0=As[kk][tm*4+0], a1=As[kk][tm*4+1], a2=As[kk][tm*4+2], a3=As[kk][tm*4+3];
        double w0=Ws[kk][tn*4+0], w1=Ws[kk][tn*4+1], w2=Ws[kk][tn*4+2], w3=Ws[kk][tn*4+3];
        acc[0][0] += a0*w0; acc[0][1] += a0*w1; acc[0][2] += a0*w2; acc[0][3] += a0*w3;
        acc[1][0] += a1*w0; acc[1][1] += a1*w1; acc[1][2] += a1*w2; acc[1][3] += a1*w3;
        acc[2][0] += a2*w0; acc[2][1] += a2*w1; acc[2][2] += a2*w2; acc[2][3] += a2*w3;
        acc[3][0] += a3*w0; acc[3][1] += a3*w1; acc[3][2] += a3*w2; acc[3][3] += a3*w3;
      }
      __syncthreads();
    }
  }
  #pragma unroll
  for(int i=0;i<4;i++){
    int gr = m0 + tm*4 + i;
    if(gr>=M) continue;
    #pragma unroll
    for(int j=0;j<4;j++){
      int gc = n0 + tn*4 + j;
      double v = acc[i][j] + (double)bias[gc];
      if(v<0.0) v=0.0;
      out[(long)gr*128 + gc] = v;
    }
  }
}

// ---------------- batchnorm ----------------
template<typename T>
__global__ void k_colstats(const T* __restrict__ x, int M, int J,
                           double* __restrict__ ps, double* __restrict__ pq){
  int c = threadIdx.x; int b = blockIdx.x, B = gridDim.x;
  int rows = (M + B - 1)/B;
  int r0 = b*rows, r1 = r0+rows; if(r1>M) r1=M;
  double s=0.0,q=0.0;
  for(int r=r0;r<r1;r++){ double v = (double)x[(long)r*J + c]; s+=v; q+=v*v; }
  ps[(long)b*J+c]=s; pq[(long)b*J+c]=q;
}

__global__ void k_bnfinal(const double* __restrict__ ps, const double* __restrict__ pq,
                          int B, int J, int M, const float* __restrict__ g,
                          const float* __restrict__ bta,
                          double* __restrict__ sc, double* __restrict__ sh){
  int c = threadIdx.x; if(c>=J) return;
  double s=0.0,q=0.0;
  for(int b=0;b<B;b++){ s+=ps[(long)b*J+c]; q+=pq[(long)b*J+c]; }
  double m = s/M; double v = q/M - m*m;
  double inv = 1.0/sqrt(v + 1e-5);
  double a = (double)g[c]*inv;
  sc[c]=a; sh[c]=(double)bta[c] - m*a;
}

__global__ void k_bnapply_f64(double* __restrict__ x, float* __restrict__ o32,
                              const double* __restrict__ sc, const double* __restrict__ sh,
                              long total, int Jm){
  long i = (long)blockIdx.x*blockDim.x + threadIdx.x;
  if(i>=total) return;
  int c = (int)(i & Jm);
  double v = x[i]*sc[c] + sh[c];
  x[i]=v; o32[i]=(float)v;
}

__global__ void k_bnapply_f32(float* __restrict__ x,
                              const double* __restrict__ sc, const double* __restrict__ sh,
                              long total, int Jm){
  long i = (long)blockIdx.x*blockDim.x + threadIdx.x;
  if(i>=total) return;
  int c = (int)(i & Jm);
  x[i] = (float)((double)x[i]*sc[c] + sh[c]);
}

// ---------------- z = mean + exp(log_std) * noise.mean(0), float4 ----------------
__global__ void k_z(const float* __restrict__ mean, const float* __restrict__ lstd,
                    const float* __restrict__ noise, float* __restrict__ z, int total4){
  int i = blockIdx.x*blockDim.x + threadIdx.x;
  if(i>=total4) return;
  const float4* m4 = (const float4*)mean;
  const float4* l4 = (const float4*)lstd;
  const float4* n4 = (const float4*)noise;
  float4 m = m4[i], l = l4[i];
  float nx=0.f, ny=0.f, nz=0.f, nw=0.f;
  #pragma unroll
  for(int s=0;s<10;s++){
    float4 v = n4[(long)s*total4 + i];
    nx+=v.x; ny+=v.y; nz+=v.z; nw+=v.w;
  }
  float4 o;
  o.x = (float)((double)m.x + exp((double)l.x)*((double)nx*0.1));
  o.y = (float)((double)m.y + exp((double)l.y)*((double)ny*0.1));
  o.z = (float)((double)m.z + exp((double)l.z)*((double)nz*0.1));
  o.w = (float)((double)m.w + exp((double)l.w)*((double)nw*0.1));
  ((float4*)z)[i] = o;
}

// ---------------- pooling score path (f64) ----------------
__global__ void k_tr(const double* __restrict__ x1, const float* __restrict__ wrel,
                     const float* __restrict__ wroot, double* __restrict__ t,
                     double* __restrict__ r, int n){
  int gid = blockIdx.x*blockDim.x + threadIdx.x;
  int node = gid>>6, lane = gid&63;
  if(node>=n) return;
  const double* row = x1 + (long)node*128;
  double a0=row[lane], a1=row[lane+64];
  double tv = a0*(double)wrel[lane]  + a1*(double)wrel[lane+64];
  double rv = a0*(double)wroot[lane] + a1*(double)wroot[lane+64];
  for(int off=32; off>0; off>>=1){
    tv += __shfl_xor(tv, off);
    rv += __shfl_xor(rv, off);
  }
  if(lane==0){ t[node]=tv; r[node]=rv; }
}

// score -> monotone u64 key (-0 normalized; tanh never NaN)
__global__ void k_score(const double* __restrict__ t, const double* __restrict__ r,
                        const int* __restrict__ csr, const int* __restrict__ rowptr,
                        const float* __restrict__ bp,
                        unsigned long long* __restrict__ key, int n){
  int i = blockIdx.x*blockDim.x + threadIdx.x;
  if(i>=n) return;
  double s = (double)bp[0] + r[i];
  int b=rowptr[i], e=rowptr[i+1];
  for(int j=b;j<e;j++) s += t[csr[j]];
  double sc = tanh(s) + 0.0;           // -0 -> +0
  long long u = __double_as_longlong(sc);
  unsigned long long uu = (unsigned long long)u;
  key[i] = (u < 0) ? ~uu : (uu ^ 0x8000000000000000ULL);
}

// ---- splitter-bucketed exact rank ----
// 1) sample 2048 keys (stride 24), bitonic-sort ascending in one block
__global__ void k_sample_sort(const unsigned long long* __restrict__ key,
                              unsigned long long* __restrict__ samp){
  __shared__ unsigned long long sm[NSAMP];
  int t = threadIdx.x;                       // 1024 threads
  sm[t]      = key[t*24];                    // 1023*24=24552
  sm[t+1024] = key[(t+1024)*24];             // 2047*24=49128 < 50000
  __syncthreads();
  for(int k=2; k<=NSAMP; k<<=1){
    for(int j=k>>1; j>0; j>>=1){
      #pragma unroll 2
      for(int base=0; base<NSAMP; base+=1024){
        int i = base + t;
        int l = i ^ j;
        if(l > i){
          unsigned long long a = sm[i], b = sm[l];
          bool up = ((i & k) == 0);
          if(up ? (a > b) : (a < b)){ sm[i]=b; sm[l]=a; }
        }
      }
      __syncthreads();
    }
  }
  samp[t] = sm[t]; samp[t+1024] = sm[t+1024];
}

// 2) bucket = lower_bound(samp, key_i) in [0, NSAMP]; equal keys -> same bucket
__global__ __launch_bounds__(256) void k_bucket_assign(
    const unsigned long long* __restrict__ key,
    const unsigned long long* __restrict__ samp,
    int* __restrict__ bucket, int* __restrict__ bcnt, int n){
  __shared__ unsigned long long sm[NSAMP];
  for(int u=threadIdx.x; u<NSAMP; u+=256) sm[u] = samp[u];
  __syncthreads();
  int i = blockIdx.x*256 + threadIdx.x;
  if(i>=n) return;
  unsigned long long ki = key[i];
  int lo=0, hi=NSAMP;
  while(lo<hi){ int mid=(lo+hi)>>1; if(sm[mid] < ki) lo=mid+1; else hi=mid; }
  bucket[i]=lo;
  atomicAdd(&bcnt[lo],1);
}

__global__ void k_bucket_fill(const int* __restrict__ bucket,
                              const int* __restrict__ bstart, int* __restrict__ bfill,
                              int* __restrict__ blist, int n){
  int i = blockIdx.x*blockDim.x + threadIdx.x;
  if(i>=n) return;
  int b = bucket[i];
  int p = bstart[b] + atomicAdd(&bfill[b],1);
  blist[p] = i;
}

// 3) per-bucket exact rank: rank = (#keys in higher buckets) + in-bucket count.
// Order-independent w.r.t. blist arrival order => deterministic.
__global__ __launch_bounds__(256) void k_bucket_rank(
    const unsigned long long* __restrict__ key,
    const int* __restrict__ blist, const int* __restrict__ bstart,
    int n, int k, int* __restrict__ keep, int* __restrict__ perm){
  __shared__ unsigned long long skey[2048];
  __shared__ int sidx[2048];
  int b = blockIdx.x;
  int s0 = bstart[b], s1 = bstart[b+1];
  int m = s1 - s0;
  if(m<=0) return;
  int above = n - s1;   // all keys in buckets > b are strictly greater
  if(m <= 2048){
    for(int u=threadIdx.x; u<m; u+=256){ int ii=blist[s0+u]; sidx[u]=ii; skey[u]=key[ii]; }
    __syncthreads();
    for(int u=threadIdx.x; u<m; u+=256){
      unsigned long long ki = skey[u]; int ii = sidx[u];
      int c = 0;
      for(int v=0; v<m; v++){
        unsigned long long kv = skey[v];
        c += ((kv > ki) || (kv == ki && sidx[v] < ii)) ? 1 : 0;
      }
      int rank = above + c;
      int kp = (rank < k) ? 1 : 0;
      keep[ii] = kp;
      if(kp) perm[rank] = ii;
    }
  } else {
    for(int u=threadIdx.x; u<m; u+=256){
      int ii = blist[s0+u];
      unsigned long long ki = key[ii];
      int c=0;
      for(int v=0; v<m; v++){
        int jj = blist[s0+v];
        unsigned long long kv = key[jj];
        c += ((kv > ki) || (kv == ki && jj < ii)) ? 1 : 0;
      }
      int rank = above + c;
      int kp = (rank < k) ? 1 : 0;
      keep[ii] = kp;
      if(kp) perm[rank] = ii;
    }
  }
}

__global__ void k_unpool(const float* __restrict__ x1, const int* __restrict__ perm,
                         float* __restrict__ out, int k){
  int i = blockIdx.x*blockDim.x + threadIdx.x;
  if(i >= k*128) return;
  int r = i>>7, c = i&127;
  out[i] = x1[(long)perm[r]*128 + c];
}

__global__ void k_edgeout(const int* __restrict__ src, const int* __restrict__ dst,
                          const int* __restrict__ keep, float* __restrict__ o2,
                          float* __restrict__ o3, int E){
  int e = blockIdx.x*blockDim.x + threadIdx.x;
  if(e>=E) return;
  int s=src[e], d=dst[e];
  bool m = keep[s] && keep[d];
  o2[e]   = m ? (float)s : -1.f;
  o2[E+e] = m ? (float)d : -1.f;
  o3[e]   = m ? 1.f : 0.f;
}

// ---------------- launch ----------------
extern "C" void kernel_launch(void* const* d_in, const int* in_sizes, int n_in,
                              void* d_out, int out_size, void* d_ws, size_t ws_size,
                              hipStream_t stream){
  const float* x     = (const float*)d_in[0];
  const int*   ei    = (const int*)d_in[1];
  const float* noise = (const float*)d_in[3];
  const float* We1l  = (const float*)d_in[4];
  const float* be1   = (const float*)d_in[5];
  const float* We1r  = (const float*)d_in[6];
  const float* g1    = (const float*)d_in[7];
  const float* b1    = (const float*)d_in[8];
  const float* We2l  = (const float*)d_in[9];
  const float* be2   = (const float*)d_in[10];
  const float* We2r  = (const float*)d_in[11];
  const float* g2    = (const float*)d_in[12];
  const float* b2    = (const float*)d_in[13];
  const float* We3l  = (const float*)d_in[14];
  const float* be3   = (const float*)d_in[15];
  const float* We3r  = (const float*)d_in[16];
  const float* Wt    = (const float*)d_in[17];
  const float* bt    = (const float*)d_in[18];
  const float* Wd1   = (const float*)d_in[19];
  const float* bd1   = (const float*)d_in[20];
  const float* gd    = (const float*)d_in[21];
  const float* bd    = (const float*)d_in[22];
  const float* Wd2   = (const float*)d_in[23];
  const float* bd2   = (const float*)d_in[24];
  const float* Wprel = (const float*)d_in[25];
  const float* bp    = (const float*)d_in[26];
  const float* Wproot= (const float*)d_in[27];

  const int* src = ei;
  const int* dst = ei + EE;

  float* out   = (float*)d_out;
  float* o_rec  = out;                 // N*64
  float* o_xun  = out + 3200000;       // k*128
  float* o_eiu  = out + 6400000;       // 2*E
  float* o_mask = out + 8000000;       // E
  float* o_mean = out + 8800000;       // N*64
  float* o_lstd = out + 12000000;      // N*64
  float* o_x1   = out + 15200000;      // N*128

  char* w = (char*)d_ws;
  size_t off = 0;
  auto alloc = [&](size_t bytes)->char*{
    char* p = w + off; off += (bytes + 255) & ~(size_t)255; return p;
  };
  int*    csr  = (int*)   alloc((size_t)EE*4);
  int*    rowp = (int*)   alloc((size_t)(NN+1)*4);
  int*    cnt  = (int*)   alloc((size_t)NN*4);
  char*   B3   =          alloc((size_t)NN*128*8);
  char*   B4   =          alloc((size_t)NN*64*8);
  char*   B5   =          alloc((size_t)NN*256*4);
  double* t_   = (double*)alloc((size_t)NN*8);
  double* r_   = (double*)alloc((size_t)NN*8);
  unsigned long long* key_ = (unsigned long long*)alloc((size_t)NN*8);
  int*    keep = (int*)   alloc((size_t)NN*4);
  int*    perm = (int*)   alloc((size_t)KHALF*4);
  double* ps   = (double*)alloc((size_t)240*256*8);
  double* pq   = (double*)alloc((size_t)240*256*8);
  double* bnsc = (double*)alloc(256*8);
  double* bnsh = (double*)alloc(256*8);
  unsigned long long* samp = (unsigned long long*)alloc((size_t)NSAMP*8);
  int*    bucket = (int*) alloc((size_t)NN*4);
  int*    bcnt   = (int*) alloc((size_t)NBK*4);
  int*    bstart = (int*) alloc((size_t)(NBK+1)*4);
  int*    bfill  = (int*) alloc((size_t)NBK*4);
  int*    blist  = (int*) alloc((size_t)NN*4);
  (void)in_sizes; (void)n_in; (void)out_size; (void)ws_size;

  double* A1  = (double*)B4;
  double* x1p = (double*)B3;
  float*  A2  = (float*)B4;
  float*  x2  = (float*)B3;
  float*  T3  = (float*)B5;
  float*  msr = (float*)(B5 + (size_t)NN*128*4);
  float*  zb  = (float*)B5;
  float*  x1t = (float*)(B5 + (size_t)NN*64*4);
  float*  h   = (float*)B4;

  // CSR build
  hipMemsetAsync(cnt, 0, (size_t)NN*4, stream);
  k_hist<<<(EE+255)/256,256,0,stream>>>(dst, cnt, EE);
  k_scan<<<1,1024,0,stream>>>(cnt, rowp, NN);
  hipMemsetAsync(cnt, 0, (size_t)NN*4, stream);
  k_fill<<<(EE+255)/256,256,0,stream>>>(src, dst, rowp, cnt, csr, EE);

  // conv1 (f64 score-critical path)
  k_segmean<double,double,64,1><<<(NN+3)/4,256,0,stream>>>(x, csr, rowp, A1, NN);
  { dim3 g((NN+63)/64, 2);
    k_gemm_c1<<<g,256,0,stream>>>(A1, x, We1l, We1r, be1, x1p, NN); }
  k_colstats<double><<<240,128,0,stream>>>(x1p, NN, 128, ps, pq);
  k_bnfinal<<<1,128,0,stream>>>(ps,pq,240,128,NN,g1,b1,bnsc,bnsh);
  { long tot=(long)NN*128;
    k_bnapply_f64<<<(int)((tot+255)/256),256,0,stream>>>(x1p, o_x1, bnsc,bnsh, tot, 127); }
  k_tr<<<(NN+3)/4,256,0,stream>>>(x1p, Wprel, Wproot, t_, r_, NN);

  // conv2 (f32)
  k_segmean<float,float,128,2><<<(NN+3)/4,256,0,stream>>>(o_x1, csr, rowp, A2, NN);
  { dim3 g((NN+63)/64, 4);
    k_gemm_f32<<<g,256,0,stream>>>(A2, We2l, 128, o_x1, We2r, 128, be2, x2, nullptr, NN, 256, 1, 0); }
  k_colstats<float><<<240,256,0,stream>>>(x2, NN, 256, ps, pq);
  k_bnfinal<<<1,256,0,stream>>>(ps,pq,240,256,NN,g2,b2,bnsc,bnsh);
  { long tot=(long)NN*256;
    k_bnapply_f32<<<(int)((tot+255)/256),256,0,stream>>>(x2, bnsc,bnsh, tot, 255); }

  // conv3 transform-first: ms = segmean(x2@We3l) + (x2@We3r + be3)
  { dim3 g((NN+63)/64, 2);
    k_gemm_f32<<<g,256,0,stream>>>(x2, We3l, 256, nullptr, nullptr, 0, nullptr, T3, nullptr, NN, 128, 0, 0); }
  { dim3 g((NN+63)/64, 2);
    k_gemm_f32<<<g,256,0,stream>>>(x2, We3r, 256, nullptr, nullptr, 0, be3, msr, nullptr, NN, 128, 0, 0); }
  k_segmean_ms<<<(NN+3)/4,256,0,stream>>>(T3, msr, csr, rowp, o_mean, o_lstd, NN);

  // decoder
  k_z<<<(800000+255)/256,256,0,stream>>>(o_mean, o_lstd, noise, zb, 800000);
  { dim3 g((NN+63)/64, 1);
    k_gemm_f32<<<g,256,0,stream>>>(o_x1, Wt, 128, nullptr, nullptr, 0, bt, x1t, nullptr, NN, 64, 0, 0); }
  { dim3 g((NN+63)/64, 2);
    k_gemm_f32<<<g,256,0,stream>>>(zb, Wd1, 64, x1t, Wd1 + 64*128, 64, bd1, h, nullptr, NN, 128, 1, 0); }
  k_colstats<float><<<240,128,0,stream>>>(h, NN, 128, ps, pq);
  k_bnfinal<<<1,128,0,stream>>>(ps,pq,240,128,NN,gd,bd,bnsc,bnsh);
  { long tot=(long)NN*128;
    k_bnapply_f32<<<(int)((tot+255)/256),256,0,stream>>>(h, bnsc,bnsh, tot, 127); }
  { dim3 g((NN+63)/64, 1);
    k_gemm_f32<<<g,256,0,stream>>>(h, Wd2, 128, nullptr, nullptr, 0, bd2, o_rec, nullptr, NN, 64, 0, 0); }

  // pooling: score/key -> splitter-bucketed exact rank -> outputs
  k_score<<<(NN+255)/256,256,0,stream>>>(t_, r_, csr, rowp, bp, key_, NN);
  k_sample_sort<<<1,1024,0,stream>>>(key_, samp);
  hipMemsetAsync(bcnt, 0, (size_t)NBK*4, stream);
  k_bucket_assign<<<(NN+255)/256,256,0,stream>>>(key_, samp, bucket, bcnt, NN);
  k_scan<<<1,1024,0,stream>>>(bcnt, bstart, NBK);
  hipMemsetAsync(bfill, 0, (size_t)NBK*4, stream);
  k_bucket_fill<<<(NN+255)/256,256,0,stream>>>(bucket, bstart, bfill, blist, NN);
  k_bucket_rank<<<NBK,256,0,stream>>>(key_, blist, bstart, NN, KHALF, keep, perm);
  k_unpool<<<(KHALF*128+255)/256,256,0,stream>>>(o_x1, perm, o_xun, KHALF);
  k_edgeout<<<(EE+255)/256,256,0,stream>>>(src, dst, keep, o_eiu, o_mask, EE);
}

// Round 5
// 1299.291 us; speedup vs baseline: 1.4771x; 1.2032x over previous
//
#include <hip/hip_runtime.h>
#include <hip/hip_bf16.h>
#include <math.h>

#define NN 50000
#define EE 800000
#define KHALF 25000
#define NSAMP 2048
#define NBK (NSAMP+1)

typedef short bf16x8 __attribute__((ext_vector_type(8)));
typedef short sh4 __attribute__((ext_vector_type(4)));
typedef float f32x4 __attribute__((ext_vector_type(4)));

static __device__ inline unsigned short f2bf(float f){
  __hip_bfloat16 h = __float2bfloat16(f);
  return __builtin_bit_cast(unsigned short, h);
}
static __device__ inline float bf2f(unsigned short u){
  unsigned int x = ((unsigned int)u)<<16;
  return __builtin_bit_cast(float, x);
}

// ---------------- CSR build ----------------
__global__ void k_hist(const int* __restrict__ dst, int* __restrict__ cnt, int E){
  int i = blockIdx.x*blockDim.x + threadIdx.x;
  if(i<E) atomicAdd(&cnt[dst[i]], 1);
}

__global__ void k_scan(const int* __restrict__ deg, int* __restrict__ rowptr, int n){
  __shared__ int sm[1024];
  int t = threadIdx.x;
  int chunk = (n + 1023) >> 10;
  int b = t*chunk; int e = b+chunk; if(b>n) b=n; if(e>n) e=n;
  int s=0;
  for(int i=b;i<e;i++) s += deg[i];
  sm[t]=s; __syncthreads();
  for(int off=1; off<1024; off<<=1){
    int add = (t>=off)? sm[t-off] : 0;
    __syncthreads();
    sm[t] += add;
    __syncthreads();
  }
  int run = sm[t]-s;
  for(int i=b;i<e;i++){ rowptr[i]=run; run += deg[i]; }
  if(t==1023) rowptr[n]=sm[1023];
}

__global__ void k_fill(const int* __restrict__ src, const int* __restrict__ dst,
                       const int* __restrict__ rowptr, int* __restrict__ cnt,
                       int* __restrict__ csr, int E){
  int i = blockIdx.x*blockDim.x + threadIdx.x;
  if(i<E){
    int d = dst[i];
    int p = rowptr[d] + atomicAdd(&cnt[d],1);
    csr[p] = src[i];
  }
}

// ---------------- segment mean (wave per node, vectorized gather) ----------------
template<typename AccT, typename OT, int F, int VW>
__global__ void k_segmean(const float* __restrict__ x, const int* __restrict__ csr,
                          const int* __restrict__ rowptr, OT* __restrict__ out, int n){
  int gid = blockIdx.x*blockDim.x + threadIdx.x;
  int node = gid >> 6; int lane = gid & 63;
  if(node>=n) return;
  int b = rowptr[node], e = rowptr[node+1];
  AccT acc[VW];
  #pragma unroll
  for(int k=0;k<VW;k++) acc[k]=(AccT)0;
  const float* xp = x + lane*VW;
  for(int j=b;j<e;j++){
    const float* row = xp + (long)csr[j]*F;
    if(VW==1){
      acc[0] += (AccT)row[0];
    } else if(VW==2){
      float2 v = *(const float2*)row;
      acc[0]+=(AccT)v.x; acc[1]+=(AccT)v.y;
    } else {
      float4 v = *(const float4*)row;
      acc[0]+=(AccT)v.x; acc[1]+=(AccT)v.y; acc[2]+=(AccT)v.z; acc[3]+=(AccT)v.w;
    }
  }
  int d = e-b; if(d<1) d=1;
  AccT inv = (AccT)1 / (AccT)d;
  #pragma unroll
  for(int k=0;k<VW;k++) out[(long)node*F + lane*VW + k] = (OT)(acc[k]*inv);
}

// segmean(T3) + msr, split-written to mean/lstd
__global__ void k_segmean_ms(const float* __restrict__ T3, const float* __restrict__ msr,
                             const int* __restrict__ csr, const int* __restrict__ rowptr,
                             float* __restrict__ omean, float* __restrict__ olstd, int n){
  int gid = blockIdx.x*blockDim.x + threadIdx.x;
  int node = gid >> 6; int lane = gid & 63;
  if(node>=n) return;
  int b = rowptr[node], e = rowptr[node+1];
  float a0=0.f, a1=0.f;
  const float* xp = T3 + lane*2;
  for(int j=b;j<e;j++){
    float2 v = *(const float2*)(xp + (long)csr[j]*128);
    a0+=v.x; a1+=v.y;
  }
  int d=e-b; if(d<1)d=1;
  float inv = 1.f/(float)d;
  float2 mv = *(const float2*)(msr + (long)node*128 + lane*2);
  float2 r; r.x = a0*inv + mv.x; r.y = a1*inv + mv.y;
  int c0 = lane*2;
  if(c0 < 64) *(float2*)(omean + (long)node*64 + c0)      = r;
  else        *(float2*)(olstd + (long)node*64 + (c0-64)) = r;
}

// ---------------- bf16x3-split MFMA GEMM ----------------
// out = act( A@W1 [+ X@W2] + bias );  A: MxK1, W1: K1xJ, X: MxK2, W2: K2xJ.
// f32 operands split into bf16 hi + bf16 lo during staging; products
// AhBh + AhBl + AlBh accumulated in f32 (error ~1e-5 rel — f32-class).
// BM=128, BN=64, BK=64; 4 waves 2x2, each 64x32; mfma_f32_16x16x32_bf16.
// LDS tiles XOR-swizzled (byte ^= (row&7)<<4) for conflict-free ds_read_b128.
__global__ __launch_bounds__(256) void k_gemm_bf16s(
    const float* __restrict__ A, const float* __restrict__ W1, int K1,
    const float* __restrict__ X, const float* __restrict__ W2, int K2,
    const float* __restrict__ bias, float* __restrict__ out,
    int M, int J, int relu)
{
  __shared__ __align__(16) short Ah[128*64];
  __shared__ __align__(16) short Al[128*64];
  __shared__ __align__(16) short Bh[64*64];
  __shared__ __align__(16) short Bl[64*64];
  const int m0 = blockIdx.x*128, n0 = blockIdx.y*64;
  const int t = threadIdx.x;
  const int lane = t & 63, wid = t >> 6;
  const int wm = wid >> 1, wn = wid & 1;

  f32x4 acc[4][2];
  #pragma unroll
  for(int i=0;i<4;i++)
    #pragma unroll
    for(int j=0;j<2;j++) acc[i][j] = (f32x4){0.f,0.f,0.f,0.f};

  const int ns1 = K1 >> 6;
  const int ns2 = X ? (K2 >> 6) : 0;
  for(int s=0; s<ns1+ns2; ++s){
    const float* P; const float* W; int K, k0;
    if(s < ns1){ P = A; W = W1; K = K1; k0 = s*64; }
    else       { P = X; W = W2; K = K2; k0 = (s-ns1)*64; }

    // stage A tile: 128 rows x 64 k (f32 -> bf16 hi/lo)
    #pragma unroll
    for(int i=0;i<8;i++){
      int f4  = t + i*256;
      int row = f4 >> 4, c4 = f4 & 15;
      int gr  = m0 + row;
      float4 v = make_float4(0.f,0.f,0.f,0.f);
      if(gr < M) v = *(const float4*)(P + (long)gr*K + k0 + c4*4);
      unsigned short h0=f2bf(v.x), h1=f2bf(v.y), h2=f2bf(v.z), h3=f2bf(v.w);
      sh4 hi = (sh4){(short)h0,(short)h1,(short)h2,(short)h3};
      sh4 lo = (sh4){(short)f2bf(v.x-bf2f(h0)), (short)f2bf(v.y-bf2f(h1)),
                     (short)f2bf(v.z-bf2f(h2)), (short)f2bf(v.w-bf2f(h3))};
      int byte = (row*128 + c4*8) ^ ((row&7)<<4);
      *(sh4*)((char*)Ah + byte) = hi;
      *(sh4*)((char*)Al + byte) = lo;
    }
    // stage B tile transposed: B_lds[n][k], 64x64
    {
      int n = t & 63, k4 = (t>>6)<<2;
      #pragma unroll
      for(int i=0;i<4;i++){
        int kb = i*16 + k4;
        const float* wp = W + (long)(k0+kb)*J + n0 + n;
        float w0 = wp[0], w1 = wp[J], w2 = wp[2*J], w3 = wp[3*J];
        unsigned short h0=f2bf(w0), h1=f2bf(w1), h2=f2bf(w2), h3=f2bf(w3);
        sh4 hi = (sh4){(short)h0,(short)h1,(short)h2,(short)h3};
        sh4 lo = (sh4){(short)f2bf(w0-bf2f(h0)), (short)f2bf(w1-bf2f(h1)),
                       (short)f2bf(w2-bf2f(h2)), (short)f2bf(w3-bf2f(h3))};
        int byte = (n*128 + kb*2) ^ ((n&7)<<4);
        *(sh4*)((char*)Bh + byte) = hi;
        *(sh4*)((char*)Bl + byte) = lo;
      }
    }
    __syncthreads();

    #pragma unroll
    for(int kk=0;kk<2;kk++){
      int kb = kk*32 + (lane>>4)*8;
      bf16x8 ahf[4], alf[4], bhf[2], blf[2];
      #pragma unroll
      for(int mf=0; mf<4; mf++){
        int r = wm*64 + mf*16 + (lane&15);
        int byte = (r*128 + kb*2) ^ ((r&7)<<4);
        ahf[mf] = *(const bf16x8*)((const char*)Ah + byte);
        alf[mf] = *(const bf16x8*)((const char*)Al + byte);
      }
      #pragma unroll
      for(int nf=0; nf<2; nf++){
        int n = wn*32 + nf*16 + (lane&15);
        int byte = (n*128 + kb*2) ^ ((n&7)<<4);
        bhf[nf] = *(const bf16x8*)((const char*)Bh + byte);
        blf[nf] = *(const bf16x8*)((const char*)Bl + byte);
      }
      #pragma unroll
      for(int mf=0; mf<4; mf++)
        #pragma unroll
        for(int nf=0; nf<2; nf++){
          acc[mf][nf] = __builtin_amdgcn_mfma_f32_16x16x32_bf16(ahf[mf], bhf[nf], acc[mf][nf], 0,0,0);
          acc[mf][nf] = __builtin_amdgcn_mfma_f32_16x16x32_bf16(ahf[mf], blf[nf], acc[mf][nf], 0,0,0);
          acc[mf][nf] = __builtin_amdgcn_mfma_f32_16x16x32_bf16(alf[mf], bhf[nf], acc[mf][nf], 0,0,0);
        }
    }
    __syncthreads();
  }

  // epilogue: C/D layout col=lane&15, row=(lane>>4)*4+q (verified m89)
  #pragma unroll
  for(int mf=0; mf<4; mf++){
    #pragma unroll
    for(int nf=0; nf<2; nf++){
      int col = n0 + wn*32 + nf*16 + (lane&15);
      #pragma unroll
      for(int q=0;q<4;q++){
        int row = m0 + wm*64 + mf*16 + (lane>>4)*4 + q;
        if(row >= M) continue;
        float v = acc[mf][nf][q] + (bias ? bias[col] : 0.f);
        if(relu) v = fmaxf(v, 0.f);
        out[(long)row*J + col] = v;
      }
    }
  }
}

// ---------------- conv1 GEMM in f64 (score-critical path) ----------------
__global__ __launch_bounds__(256) void k_gemm_c1(
    const double* __restrict__ A1, const float* __restrict__ X,
    const float* __restrict__ W1, const float* __restrict__ W2,
    const float* __restrict__ bias, double* __restrict__ out, int M)
{
  __shared__ double As[32][66];
  __shared__ double Ws[32][64];
  const int m0 = blockIdx.x*64, n0 = blockIdx.y*64;
  const int t = threadIdx.x;
  const int tm = t & 15, tn = t >> 4;
  double acc[4][4];
  #pragma unroll
  for(int i=0;i<4;i++)
    #pragma unroll
    for(int j=0;j<4;j++) acc[i][j]=0.0;

  for(int pair=0; pair<2; pair++){
    const float* Wp = pair ? W2 : W1;
    for(int k0=0; k0<64; k0+=32){
      #pragma unroll
      for(int i=0;i<8;i++){
        int idx = t + i*256;
        int r = idx >> 5, c = idx & 31;
        int gr = m0 + r;
        double v = 0.0;
        if(gr<M) v = pair ? (double)X[(long)gr*64 + k0 + c] : A1[(long)gr*64 + k0 + c];
        As[c][r] = v;
      }
      #pragma unroll
      for(int i=0;i<8;i++){
        int idx = t + i*256;
        int r = idx >> 6, c = idx & 63;
        Ws[r][c] = (double)Wp[(k0+r)*128 + n0 + c];
      }
      __syncthreads();
      #pragma unroll
      for(int kk=0;kk<32;kk++){
        double a0=As[kk][tm*4+0], a1=As[kk][tm*4+1], a2=As[kk][tm*4+2], a3=As[kk][tm*4+3];
        double w0=Ws[kk][tn*4+0], w1=Ws[kk][tn*4+1], w2=Ws[kk][tn*4+2], w3=Ws[kk][tn*4+3];
        acc[0][0] += a0*w0; acc[0][1] += a0*w1; acc[0][2] += a0*w2; acc[0][3] += a0*w3;
        acc[1][0] += a1*w0; acc[1][1] += a1*w1; acc[1][2] += a1*w2; acc[1][3] += a1*w3;
        acc[2][0] += a2*w0; acc[2][1] += a2*w1; acc[2][2] += a2*w2; acc[2][3] += a2*w3;
        acc[3][0] += a3*w0; acc[3][1] += a3*w1; acc[3][2] += a3*w2; acc[3][3] += a3*w3;
      }
      __syncthreads();
    }
  }
  #pragma unroll
  for(int i=0;i<4;i++){
    int gr = m0 + tm*4 + i;
    if(gr>=M) continue;
    #pragma unroll
    for(int j=0;j<4;j++){
      int gc = n0 + tn*4 + j;
      double v = acc[i][j] + (double)bias[gc];
      if(v<0.0) v=0.0;
      out[(long)gr*128 + gc] = v;
    }
  }
}

// ---------------- batchnorm ----------------
template<typename T>
__global__ void k_colstats(const T* __restrict__ x, int M, int J,
                           double* __restrict__ ps, double* __restrict__ pq){
  int c = threadIdx.x; int b = blockIdx.x, B = gridDim.x;
  int rows = (M + B - 1)/B;
  int r0 = b*rows, r1 = r0+rows; if(r1>M) r1=M;
  double s=0.0,q=0.0;
  for(int r=r0;r<r1;r++){ double v = (double)x[(long)r*J + c]; s+=v; q+=v*v; }
  ps[(long)b*J+c]=s; pq[(long)b*J+c]=q;
}

__global__ void k_bnfinal(const double* __restrict__ ps, const double* __restrict__ pq,
                          int B, int J, int M, const float* __restrict__ g,
                          const float* __restrict__ bta,
                          double* __restrict__ sc, double* __restrict__ sh){
  int c = threadIdx.x; if(c>=J) return;
  double s=0.0,q=0.0;
  for(int b=0;b<B;b++){ s+=ps[(long)b*J+c]; q+=pq[(long)b*J+c]; }
  double m = s/M; double v = q/M - m*m;
  double inv = 1.0/sqrt(v + 1e-5);
  double a = (double)g[c]*inv;
  sc[c]=a; sh[c]=(double)bta[c] - m*a;
}

__global__ void k_bnapply_f64(double* __restrict__ x, float* __restrict__ o32,
                              const double* __restrict__ sc, const double* __restrict__ sh,
                              long total, int Jm){
  long i = (long)blockIdx.x*blockDim.x + threadIdx.x;
  if(i>=total) return;
  int c = (int)(i & Jm);
  double v = x[i]*sc[c] + sh[c];
  x[i]=v; o32[i]=(float)v;
}

__global__ void k_bnapply_f32(float* __restrict__ x,
                              const double* __restrict__ sc, const double* __restrict__ sh,
                              long total, int Jm){
  long i = (long)blockIdx.x*blockDim.x + threadIdx.x;
  if(i>=total) return;
  int c = (int)(i & Jm);
  x[i] = (float)((double)x[i]*sc[c] + sh[c]);
}

// ---------------- z = mean + exp(log_std) * noise.mean(0), float4 ----------------
__global__ void k_z(const float* __restrict__ mean, const float* __restrict__ lstd,
                    const float* __restrict__ noise, float* __restrict__ z, int total4){
  int i = blockIdx.x*blockDim.x + threadIdx.x;
  if(i>=total4) return;
  const float4* m4 = (const float4*)mean;
  const float4* l4 = (const float4*)lstd;
  const float4* n4 = (const float4*)noise;
  float4 m = m4[i], l = l4[i];
  float nx=0.f, ny=0.f, nz=0.f, nw=0.f;
  #pragma unroll
  for(int s=0;s<10;s++){
    float4 v = n4[(long)s*total4 + i];
    nx+=v.x; ny+=v.y; nz+=v.z; nw+=v.w;
  }
  float4 o;
  o.x = (float)((double)m.x + exp((double)l.x)*((double)nx*0.1));
  o.y = (float)((double)m.y + exp((double)l.y)*((double)ny*0.1));
  o.z = (float)((double)m.z + exp((double)l.z)*((double)nz*0.1));
  o.w = (float)((double)m.w + exp((double)l.w)*((double)nw*0.1));
  ((float4*)z)[i] = o;
}

// ---------------- pooling score path (f64) ----------------
__global__ void k_tr(const double* __restrict__ x1, const float* __restrict__ wrel,
                     const float* __restrict__ wroot, double* __restrict__ t,
                     double* __restrict__ r, int n){
  int gid = blockIdx.x*blockDim.x + threadIdx.x;
  int node = gid>>6, lane = gid&63;
  if(node>=n) return;
  const double* row = x1 + (long)node*128;
  double a0=row[lane], a1=row[lane+64];
  double tv = a0*(double)wrel[lane]  + a1*(double)wrel[lane+64];
  double rv = a0*(double)wroot[lane] + a1*(double)wroot[lane+64];
  for(int off=32; off>0; off>>=1){
    tv += __shfl_xor(tv, off);
    rv += __shfl_xor(rv, off);
  }
  if(lane==0){ t[node]=tv; r[node]=rv; }
}

// score -> monotone u64 key (-0 normalized; tanh never NaN)
__global__ void k_score(const double* __restrict__ t, const double* __restrict__ r,
                        const int* __restrict__ csr, const int* __restrict__ rowptr,
                        const float* __restrict__ bp,
                        unsigned long long* __restrict__ key, int n){
  int i = blockIdx.x*blockDim.x + threadIdx.x;
  if(i>=n) return;
  double s = (double)bp[0] + r[i];
  int b=rowptr[i], e=rowptr[i+1];
  for(int j=b;j<e;j++) s += t[csr[j]];
  double sc = tanh(s) + 0.0;           // -0 -> +0
  long long u = __double_as_longlong(sc);
  unsigned long long uu = (unsigned long long)u;
  key[i] = (u < 0) ? ~uu : (uu ^ 0x8000000000000000ULL);
}

// ---- splitter-bucketed exact rank ----
__global__ void k_sample_sort(const unsigned long long* __restrict__ key,
                              unsigned long long* __restrict__ samp){
  __shared__ unsigned long long sm[NSAMP];
  int t = threadIdx.x;
  sm[t]      = key[t*24];
  sm[t+1024] = key[(t+1024)*24];
  __syncthreads();
  for(int k=2; k<=NSAMP; k<<=1){
    for(int j=k>>1; j>0; j>>=1){
      #pragma unroll 2
      for(int base=0; base<NSAMP; base+=1024){
        int i = base + t;
        int l = i ^ j;
        if(l > i){
          unsigned long long a = sm[i], b = sm[l];
          bool up = ((i & k) == 0);
          if(up ? (a > b) : (a < b)){ sm[i]=b; sm[l]=a; }
        }
      }
      __syncthreads();
    }
  }
  samp[t] = sm[t]; samp[t+1024] = sm[t+1024];
}

__global__ __launch_bounds__(256) void k_bucket_assign(
    const unsigned long long* __restrict__ key,
    const unsigned long long* __restrict__ samp,
    int* __restrict__ bucket, int* __restrict__ bcnt, int n){
  __shared__ unsigned long long sm[NSAMP];
  for(int u=threadIdx.x; u<NSAMP; u+=256) sm[u] = samp[u];
  __syncthreads();
  int i = blockIdx.x*256 + threadIdx.x;
  if(i>=n) return;
  unsigned long long ki = key[i];
  int lo=0, hi=NSAMP;
  while(lo<hi){ int mid=(lo+hi)>>1; if(sm[mid] < ki) lo=mid+1; else hi=mid; }
  bucket[i]=lo;
  atomicAdd(&bcnt[lo],1);
}

__global__ void k_bucket_fill(const int* __restrict__ bucket,
                              const int* __restrict__ bstart, int* __restrict__ bfill,
                              int* __restrict__ blist, int n){
  int i = blockIdx.x*blockDim.x + threadIdx.x;
  if(i>=n) return;
  int b = bucket[i];
  int p = bstart[b] + atomicAdd(&bfill[b],1);
  blist[p] = i;
}

__global__ __launch_bounds__(256) void k_bucket_rank(
    const unsigned long long* __restrict__ key,
    const int* __restrict__ blist, const int* __restrict__ bstart,
    int n, int k, int* __restrict__ keep, int* __restrict__ perm){
  __shared__ unsigned long long skey[2048];
  __shared__ int sidx[2048];
  int b = blockIdx.x;
  int s0 = bstart[b], s1 = bstart[b+1];
  int m = s1 - s0;
  if(m<=0) return;
  int above = n - s1;
  if(m <= 2048){
    for(int u=threadIdx.x; u<m; u+=256){ int ii=blist[s0+u]; sidx[u]=ii; skey[u]=key[ii]; }
    __syncthreads();
    for(int u=threadIdx.x; u<m; u+=256){
      unsigned long long ki = skey[u]; int ii = sidx[u];
      int c = 0;
      for(int v=0; v<m; v++){
        unsigned long long kv = skey[v];
        c += ((kv > ki) || (kv == ki && sidx[v] < ii)) ? 1 : 0;
      }
      int rank = above + c;
      int kp = (rank < k) ? 1 : 0;
      keep[ii] = kp;
      if(kp) perm[rank] = ii;
    }
  } else {
    for(int u=threadIdx.x; u<m; u+=256){
      int ii = blist[s0+u];
      unsigned long long ki = key[ii];
      int c=0;
      for(int v=0; v<m; v++){
        int jj = blist[s0+v];
        unsigned long long kv = key[jj];
        c += ((kv > ki) || (kv == ki && jj < ii)) ? 1 : 0;
      }
      int rank = above + c;
      int kp = (rank < k) ? 1 : 0;
      keep[ii] = kp;
      if(kp) perm[rank] = ii;
    }
  }
}

__global__ void k_unpool(const float* __restrict__ x1, const int* __restrict__ perm,
                         float* __restrict__ out, int k){
  int i = blockIdx.x*blockDim.x + threadIdx.x;
  if(i >= k*128) return;
  int r = i>>7, c = i&127;
  out[i] = x1[(long)perm[r]*128 + c];
}

__global__ void k_edgeout(const int* __restrict__ src, const int* __restrict__ dst,
                          const int* __restrict__ keep, float* __restrict__ o2,
                          float* __restrict__ o3, int E){
  int e = blockIdx.x*blockDim.x + threadIdx.x;
  if(e>=E) return;
  int s=src[e], d=dst[e];
  bool m = keep[s] && keep[d];
  o2[e]   = m ? (float)s : -1.f;
  o2[E+e] = m ? (float)d : -1.f;
  o3[e]   = m ? 1.f : 0.f;
}

// ---------------- launch ----------------
extern "C" void kernel_launch(void* const* d_in, const int* in_sizes, int n_in,
                              void* d_out, int out_size, void* d_ws, size_t ws_size,
                              hipStream_t stream){
  const float* x     = (const float*)d_in[0];
  const int*   ei    = (const int*)d_in[1];
  const float* noise = (const float*)d_in[3];
  const float* We1l  = (const float*)d_in[4];
  const float* be1   = (const float*)d_in[5];
  const float* We1r  = (const float*)d_in[6];
  const float* g1    = (const float*)d_in[7];
  const float* b1    = (const float*)d_in[8];
  const float* We2l  = (const float*)d_in[9];
  const float* be2   = (const float*)d_in[10];
  const float* We2r  = (const float*)d_in[11];
  const float* g2    = (const float*)d_in[12];
  const float* b2    = (const float*)d_in[13];
  const float* We3l  = (const float*)d_in[14];
  const float* be3   = (const float*)d_in[15];
  const float* We3r  = (const float*)d_in[16];
  const float* Wt    = (const float*)d_in[17];
  const float* bt    = (const float*)d_in[18];
  const float* Wd1   = (const float*)d_in[19];
  const float* bd1   = (const float*)d_in[20];
  const float* gd    = (const float*)d_in[21];
  const float* bd    = (const float*)d_in[22];
  const float* Wd2   = (const float*)d_in[23];
  const float* bd2   = (const float*)d_in[24];
  const float* Wprel = (const float*)d_in[25];
  const float* bp    = (const float*)d_in[26];
  const float* Wproot= (const float*)d_in[27];

  const int* src = ei;
  const int* dst = ei + EE;

  float* out   = (float*)d_out;
  float* o_rec  = out;                 // N*64
  float* o_xun  = out + 3200000;       // k*128
  float* o_eiu  = out + 6400000;       // 2*E
  float* o_mask = out + 8000000;       // E
  float* o_mean = out + 8800000;       // N*64
  float* o_lstd = out + 12000000;      // N*64
  float* o_x1   = out + 15200000;      // N*128

  char* w = (char*)d_ws;
  size_t off = 0;
  auto alloc = [&](size_t bytes)->char*{
    char* p = w + off; off += (bytes + 255) & ~(size_t)255; return p;
  };
  int*    csr  = (int*)   alloc((size_t)EE*4);
  int*    rowp = (int*)   alloc((size_t)(NN+1)*4);
  int*    cnt  = (int*)   alloc((size_t)NN*4);
  char*   B3   =          alloc((size_t)NN*128*8);
  char*   B4   =          alloc((size_t)NN*64*8);
  char*   B5   =          alloc((size_t)NN*256*4);
  double* t_   = (double*)alloc((size_t)NN*8);
  double* r_   = (double*)alloc((size_t)NN*8);
  unsigned long long* key_ = (unsigned long long*)alloc((size_t)NN*8);
  int*    keep = (int*)   alloc((size_t)NN*4);
  int*    perm = (int*)   alloc((size_t)KHALF*4);
  double* ps   = (double*)alloc((size_t)240*256*8);
  double* pq   = (double*)alloc((size_t)240*256*8);
  double* bnsc = (double*)alloc(256*8);
  double* bnsh = (double*)alloc(256*8);
  unsigned long long* samp = (unsigned long long*)alloc((size_t)NSAMP*8);
  int*    bucket = (int*) alloc((size_t)NN*4);
  int*    bcnt   = (int*) alloc((size_t)NBK*4);
  int*    bstart = (int*) alloc((size_t)(NBK+1)*4);
  int*    bfill  = (int*) alloc((size_t)NBK*4);
  int*    blist  = (int*) alloc((size_t)NN*4);
  (void)in_sizes; (void)n_in; (void)out_size; (void)ws_size;

  double* A1  = (double*)B4;
  double* x1p = (double*)B3;
  float*  A2  = (float*)B4;
  float*  x2  = (float*)B3;
  float*  T3  = (float*)B5;
  float*  msr = (float*)(B5 + (size_t)NN*128*4);
  float*  zb  = (float*)B5;
  float*  x1t = (float*)(B5 + (size_t)NN*64*4);
  float*  h   = (float*)B4;

  const int GX = (NN+127)/128;   // 391

  // CSR build
  hipMemsetAsync(cnt, 0, (size_t)NN*4, stream);
  k_hist<<<(EE+255)/256,256,0,stream>>>(dst, cnt, EE);
  k_scan<<<1,1024,0,stream>>>(cnt, rowp, NN);
  hipMemsetAsync(cnt, 0, (size_t)NN*4, stream);
  k_fill<<<(EE+255)/256,256,0,stream>>>(src, dst, rowp, cnt, csr, EE);

  // conv1 (f64 score-critical path)
  k_segmean<double,double,64,1><<<(NN+3)/4,256,0,stream>>>(x, csr, rowp, A1, NN);
  { dim3 g((NN+63)/64, 2);
    k_gemm_c1<<<g,256,0,stream>>>(A1, x, We1l, We1r, be1, x1p, NN); }
  k_colstats<double><<<240,128,0,stream>>>(x1p, NN, 128, ps, pq);
  k_bnfinal<<<1,128,0,stream>>>(ps,pq,240,128,NN,g1,b1,bnsc,bnsh);
  { long tot=(long)NN*128;
    k_bnapply_f64<<<(int)((tot+255)/256),256,0,stream>>>(x1p, o_x1, bnsc,bnsh, tot, 127); }
  k_tr<<<(NN+3)/4,256,0,stream>>>(x1p, Wprel, Wproot, t_, r_, NN);

  // conv2 (bf16x3 MFMA)
  k_segmean<float,float,128,2><<<(NN+3)/4,256,0,stream>>>(o_x1, csr, rowp, A2, NN);
  { dim3 g(GX, 4);
    k_gemm_bf16s<<<g,256,0,stream>>>(A2, We2l, 128, o_x1, We2r, 128, be2, x2, NN, 256, 1); }
  k_colstats<float><<<240,256,0,stream>>>(x2, NN, 256, ps, pq);
  k_bnfinal<<<1,256,0,stream>>>(ps,pq,240,256,NN,g2,b2,bnsc,bnsh);
  { long tot=(long)NN*256;
    k_bnapply_f32<<<(int)((tot+255)/256),256,0,stream>>>(x2, bnsc,bnsh, tot, 255); }

  // conv3 transform-first: ms = segmean(x2@We3l) + (x2@We3r + be3)
  { dim3 g(GX, 2);
    k_gemm_bf16s<<<g,256,0,stream>>>(x2, We3l, 256, nullptr, nullptr, 0, nullptr, T3, NN, 128, 0); }
  { dim3 g(GX, 2);
    k_gemm_bf16s<<<g,256,0,stream>>>(x2, We3r, 256, nullptr, nullptr, 0, be3, msr, NN, 128, 0); }
  k_segmean_ms<<<(NN+3)/4,256,0,stream>>>(T3, msr, csr, rowp, o_mean, o_lstd, NN);

  // decoder
  k_z<<<(800000+255)/256,256,0,stream>>>(o_mean, o_lstd, noise, zb, 800000);
  { dim3 g(GX, 1);
    k_gemm_bf16s<<<g,256,0,stream>>>(o_x1, Wt, 128, nullptr, nullptr, 0, bt, x1t, NN, 64, 0); }
  { dim3 g(GX, 2);
    k_gemm_bf16s<<<g,256,0,stream>>>(zb, Wd1, 64, x1t, Wd1 + 64*128, 64, bd1, h, NN, 128, 1); }
  k_colstats<float><<<240,128,0,stream>>>(h, NN, 128, ps, pq);
  k_bnfinal<<<1,128,0,stream>>>(ps,pq,240,128,NN,gd,bd,bnsc,bnsh);
  { long tot=(long)NN*128;
    k_bnapply_f32<<<(int)((tot+255)/256),256,0,stream>>>(h, bnsc,bnsh, tot, 127); }
  { dim3 g(GX, 1);
    k_gemm_bf16s<<<g,256,0,stream>>>(h, Wd2, 128, nullptr, nullptr, 0, bd2, o_rec, NN, 64, 0); }

  // pooling: score/key -> splitter-bucketed exact rank -> outputs
  k_score<<<(NN+255)/256,256,0,stream>>>(t_, r_, csr, rowp, bp, key_, NN);
  k_sample_sort<<<1,1024,0,stream>>>(key_, samp);
  hipMemsetAsync(bcnt, 0, (size_t)NBK*4, stream);
  k_bucket_assign<<<(NN+255)/256,256,0,stream>>>(key_, samp, bucket, bcnt, NN);
  k_scan<<<1,1024,0,stream>>>(bcnt, bstart, NBK);
  hipMemsetAsync(bfill, 0, (size_t)NBK*4, stream);
  k_bucket_fill<<<(NN+255)/256,256,0,stream>>>(bucket, bstart, bfill, blist, NN);
  k_bucket_rank<<<NBK,256,0,stream>>>(key_, blist, bstart, NN, KHALF, keep, perm);
  k_unpool<<<(KHALF*128+255)/256,256,0,stream>>>(o_x1, perm, o_xun, KHALF);
  k_edgeout<<<(EE+255)/256,256,0,stream>>>(src, dst, keep, o_eiu, o_mask, EE);
}